// Round 20
// baseline (200.325 us; speedup 1.0000x reference)
//
#include <hip/hip_runtime.h>
#include <hip/hip_bf16.h>

typedef __bf16 bf16_t;
typedef __bf16 bf16x8 __attribute__((ext_vector_type(8)));
typedef float  f32x4  __attribute__((ext_vector_type(4)));

#define DM    512
#define NQKV  1536
#define NTOK  65536
#define TM    48          // tokens per block (3 x 16 m-frags)
#define QSTR  1544        // qkv LDS row stride (elems): 1536 + 8 pad

// Fragment-major repacked weights ("flatmm shuffle"): for wave w (0..7),
// K-step s (0..15), ni (0..11), lane l (0..63), elem e (0..7):
//   ELEM offset = (((w*16+s)*12+ni)*64 + l)*8 + e
//   n = w*192+ni*16+(l&15);  k = s*32+(l>>4)*8+e
// Half-step h (s=h>>1, half=h&1): 6 frags at ELEM offset w*98304 + h*3072.
__device__ __align__(16) bf16_t g_wt2[(size_t)NQKV * DM];

#define MEMFENCE asm volatile("" ::: "memory")

typedef const void __attribute__((address_space(1)))* gas_t;
typedef void       __attribute__((address_space(3)))* sas_t;
__device__ __forceinline__ void gl_lds16(const void* g, void* s) {
    // async global->LDS, 16B/lane; LDS dest = wave-uniform base + lane*16
    __builtin_amdgcn_global_load_lds((gas_t)g, (sas_t)s, 16, 0, 0);
}

// ---------------------------------------------------------------------------
// Kernel 1: scatter W_q|W_k|W_v (fp32 [k][n]) -> g_wt2 fragment-major bf16
// ---------------------------------------------------------------------------
__global__ void prep_w2(const float* __restrict__ Wq,
                        const float* __restrict__ Wk,
                        const float* __restrict__ Wv) {
    int flat = blockIdx.x * 256 + threadIdx.x;   // 0..98303 (one bf16x8 each)
    int l  = flat & 63;
    int kg = l >> 4, lr = l & 15;
    int t2 = flat >> 6;
    int ni = t2 % 12;
    int t3 = t2 / 12;
    int s  = t3 & 15, w = t3 >> 4;
    int n  = w * 192 + ni * 16 + lr;             // 0..1535
    int k0 = s * 32 + kg * 8;
    int mat = n >> 9, nn = n & 511;
    const float* W = (mat == 0) ? Wq : ((mat == 1) ? Wk : Wv);
    bf16x8 v;
#pragma unroll
    for (int e = 0; e < 8; ++e) v[e] = (bf16_t)W[(k0 + e) * DM + nn];
    *(bf16x8*)(g_wt2 + (size_t)flat * 8) = v;
}

// ---------------------------------------------------------------------------
// Kernel 2: fused QKV projection + cross-head attention (R19 structure +
// K-STEP ROTATION). Accumulation over k is order-independent, so block b
// starts its weight stream at even half-step h0 = (b&15)*2 and wraps mod 32.
// Concurrent CUs on an XCD then read DIFFERENT weight lines (different L2
// banks) instead of marching the same 1.5 MB in lockstep — attacks the
// same-line bank serialization while keeping all reads within the
// generation window (L2-resident; R18 showed over-decorrelation re-fetches
// from HBM). Ring slot parity uses local h (h0 even => acc halves align).
// ---------------------------------------------------------------------------
__global__ __launch_bounds__(512, 1) void fused_mha(
    const float* __restrict__ x, float* __restrict__ out) {
    extern __shared__ char sm[];        // 148224 B

    const int tid = threadIdx.x;
    const int l   = tid & 63, w = tid >> 6;
    const int lr  = l & 15,  kg = l >> 4;
    const size_t tok0 = (size_t)blockIdx.x * TM;
    const int ntb = (int)(((size_t)NTOK - tok0) < TM ? (NTOK - tok0) : TM);
    const int h0 = (blockIdx.x & 15) << 1;        // even rotation offset
    const int s0 = h0 >> 1;                       // K-step rotation

    // ---- stage x tile: fp32 global -> bf16 LDS, 16B-chunk XOR swizzle ------
    {
        const int rbase = tid >> 5;               // 0..15
        const int cj    = tid & 31;
#pragma unroll
        for (int p = 0; p < 3; ++p) {
            int r = p * 16 + rbase;               // 0..47
            int r7 = r & 7;
            if (r < ntb) {
                const float* xp = x + (tok0 + r) * DM;
#pragma unroll
                for (int jj = 0; jj < 2; ++jj) {
                    int c = cj + jj * 32;         // chunk 0..63 (8 bf16 each)
                    float4 f0 = *(const float4*)(xp + c * 8);
                    float4 f1 = *(const float4*)(xp + c * 8 + 4);
                    bf16x8 v;
                    v[0] = (bf16_t)f0.x; v[1] = (bf16_t)f0.y;
                    v[2] = (bf16_t)f0.z; v[3] = (bf16_t)f0.w;
                    v[4] = (bf16_t)f1.x; v[5] = (bf16_t)f1.y;
                    v[6] = (bf16_t)f1.z; v[7] = (bf16_t)f1.w;
                    *(bf16x8*)(sm + r * 1024 + ((c ^ r7) << 4)) = v;
                }
            } else {                               // remainder block: zero rows
                bf16x8 z;
#pragma unroll
                for (int e = 0; e < 8; ++e) z[e] = (bf16_t)0.f;
#pragma unroll
                for (int jj = 0; jj < 2; ++jj) {
                    int c = cj + jj * 32;
                    *(bf16x8*)(sm + r * 1024 + ((c ^ r7) << 4)) = z;
                }
            }
        }
    }

    // ---- B ring: 2 slots x 6144 B per wave at sm+49152 --------------------
    const bf16_t* gwB = g_wt2 + (size_t)w * 98304 + l * 8;   // elem offsets
    char* ringW = sm + 49152 + w * 12288;                     // wave-uniform

// slot index = local parity (h_&1); SOURCE k-position rotated by h0
#define ISSUE6(h_)                                                            \
    do {                                                                      \
        _Pragma("unroll")                                                     \
        for (int ii = 0; ii < 6; ++ii)                                        \
            gl_lds16(gwB + (size_t)((((h_) + h0) & 31)) * 3072 + ii * 512,    \
                     ringW + ((h_) & 1) * 6144 + ii * 1024);                  \
    } while (0)
#define WAITVM(n_) asm volatile("s_waitcnt vmcnt(" #n_ ")" ::: "memory")

    // prologue: half-steps 0,1 in flight before the staging barrier
    ISSUE6(0); ISSUE6(1);
    asm volatile("s_waitcnt lgkmcnt(0)" ::: "memory");  // x ds_writes drained
    __builtin_amdgcn_s_barrier();
    MEMFENCE;

    // ---- barrier-free K-loop: 32 half-steps, fully unrolled ----------------
    f32x4 acc[3][12];
#pragma unroll
    for (int a = 0; a < 3; ++a)
#pragma unroll
        for (int b = 0; b < 12; ++b) acc[a][b] = (f32x4){0.f, 0.f, 0.f, 0.f};

    const int sx = (lr & 7) << 4;               // A-read swizzle term
    bf16x8 af[3];

#define HSTEP(h_, vm_)                                                        \
    do {                                                                      \
        WAITVM(vm_);              /* slot h_'s 6 stage-loads retired */       \
        bf16x8 bf_[6];                                                        \
        _Pragma("unroll")                                                     \
        for (int ni = 0; ni < 6; ++ni)                                        \
            bf_[ni] = *(const bf16x8*)(ringW + ((h_) & 1) * 6144 +            \
                                       ni * 1024 + l * 16);                   \
        if (((h_) & 1) == 0) {                                                \
            int sk_ = ((((h_) >> 1) + s0) & 15);  /* rotated K-step */        \
            _Pragma("unroll")                                                 \
            for (int mi = 0; mi < 3; ++mi)                                    \
                af[mi] = *(const bf16x8*)(sm + (mi * 16 + lr) * 1024 +        \
                                          ((sk_ * 64 + kg * 16) ^ sx));       \
        }                                                                     \
        asm volatile("s_waitcnt lgkmcnt(0)" ::: "memory");                    \
        __builtin_amdgcn_sched_barrier(0);      /* rule #18 */                \
        if ((h_) + 2 < 32) ISSUE6((h_) + 2);    /* refill freed slot */       \
        __builtin_amdgcn_s_setprio(1);                                        \
        _Pragma("unroll")                                                     \
        for (int mi = 0; mi < 3; ++mi)                                        \
        _Pragma("unroll")                                                     \
        for (int ni = 0; ni < 6; ++ni)                                        \
            acc[mi][((h_) & 1) * 6 + ni] =                                    \
                __builtin_amdgcn_mfma_f32_16x16x32_bf16(                      \
                    af[mi], bf_[ni], acc[mi][((h_) & 1) * 6 + ni], 0, 0, 0);  \
        __builtin_amdgcn_s_setprio(0);                                        \
    } while (0)

    HSTEP( 0, 6); HSTEP( 1, 6); HSTEP( 2, 6); HSTEP( 3, 6);
    HSTEP( 4, 6); HSTEP( 5, 6); HSTEP( 6, 6); HSTEP( 7, 6);
    HSTEP( 8, 6); HSTEP( 9, 6); HSTEP(10, 6); HSTEP(11, 6);
    HSTEP(12, 6); HSTEP(13, 6); HSTEP(14, 6); HSTEP(15, 6);
    HSTEP(16, 6); HSTEP(17, 6); HSTEP(18, 6); HSTEP(19, 6);
    HSTEP(20, 6); HSTEP(21, 6); HSTEP(22, 6); HSTEP(23, 6);
    HSTEP(24, 6); HSTEP(25, 6); HSTEP(26, 6); HSTEP(27, 6);
    HSTEP(28, 6); HSTEP(29, 6); HSTEP(30, 6); HSTEP(31, 0);
#undef HSTEP
#undef ISSUE6
#undef WAITVM

    // ---- A + ring dead; full drain + sync before qkv overlays --------------
    asm volatile("s_waitcnt vmcnt(0) lgkmcnt(0)" ::: "memory");
    __builtin_amdgcn_s_barrier();
    MEMFENCE;

    // ---- epilogue: acc -> qkv LDS [48][QSTR] (row = token, col = n) --------
    bf16_t* qkv = (bf16_t*)sm;
#pragma unroll
    for (int mi = 0; mi < 3; ++mi)
#pragma unroll
        for (int ni = 0; ni < 12; ++ni) {
            int col = w * 192 + ni * 16 + lr;
#pragma unroll
            for (int i = 0; i < 4; ++i) {
                int token = mi * 16 + kg * 4 + i;
                qkv[token * QSTR + col] = (bf16_t)acc[mi][ni][i];
            }
        }
    asm volatile("s_waitcnt lgkmcnt(0)" ::: "memory");
    __builtin_amdgcn_s_barrier();
    MEMFENCE;

    // ---- attention: 16 threads/token, two passes (0..31, 32..47) ----------
#pragma unroll
    for (int p = 0; p < 2; ++p) {
        const int tok = p * 32 + (tid >> 4);
        if (tok < ntb) {
            const int tj = tid & 15, h = tj & 7, d0 = (tj >> 3) << 5;
            const bf16_t* base = qkv + tok * QSTR;

            float qv[32];
            {
                const bf16_t* qp = base + h * 64 + d0;
#pragma unroll
                for (int j = 0; j < 4; ++j) {
                    bf16x8 q8 = *(const bf16x8*)(qp + 8 * j);
#pragma unroll
                    for (int e = 0; e < 8; ++e) qv[8 * j + e] = (float)q8[e];
                }
            }

            float s[8];
#pragma unroll
            for (int t = 0; t < 8; ++t) {
                const bf16_t* kp = base + 512 + t * 64 + d0;
                float a = 0.f;
#pragma unroll
                for (int j = 0; j < 4; ++j) {
                    bf16x8 k8 = *(const bf16x8*)(kp + 8 * j);
#pragma unroll
                    for (int e = 0; e < 8; ++e) a += qv[8 * j + e] * (float)k8[e];
                }
                s[t] = a;
            }
            // combine two d-halves (partner lane tid^8: same tok, same h)
#pragma unroll
            for (int t = 0; t < 8; ++t) s[t] += __shfl_xor(s[t], 8, 64);

            float m = s[0];
#pragma unroll
            for (int t = 1; t < 8; ++t) m = fmaxf(m, s[t]);
            float pr[8], psum = 0.f;
#pragma unroll
            for (int t = 0; t < 8; ++t) {
                pr[t] = exp2f((s[t] - m) * 1.44269504088896f);
                psum += pr[t];
            }
            float inv = 1.0f / psum;

            float o[32];
#pragma unroll
            for (int e = 0; e < 32; ++e) o[e] = 0.f;
#pragma unroll
            for (int t = 0; t < 8; ++t) {
                float pt = pr[t] * inv;
                const bf16_t* vp = base + 1024 + t * 64 + d0;
#pragma unroll
                for (int j = 0; j < 4; ++j) {
                    bf16x8 v8 = *(const bf16x8*)(vp + 8 * j);
#pragma unroll
                    for (int e = 0; e < 8; ++e) o[8 * j + e] += pt * (float)v8[e];
                }
            }

            float* op = out + (tok0 + tok) * DM + h * 64 + d0;
#pragma unroll
            for (int j = 0; j < 8; ++j) {
                float4 o4 = {o[4 * j], o[4 * j + 1], o[4 * j + 2], o[4 * j + 3]};
                *(float4*)(op + 4 * j) = o4;
            }
        }
    }
}

// ---------------------------------------------------------------------------
extern "C" void kernel_launch(void* const* d_in, const int* in_sizes, int n_in,
                              void* d_out, int out_size, void* d_ws, size_t ws_size,
                              hipStream_t stream) {
    (void)d_ws; (void)ws_size; (void)n_in; (void)out_size;
    const float* x  = (const float*)d_in[0];
    const float* Wq = (const float*)d_in[1];
    const float* Wk = (const float*)d_in[2];
    const float* Wv = (const float*)d_in[3];
    float* out = (float*)d_out;

    int ntok = in_sizes[0] / DM;                   // 65536
    int grid = (ntok + TM - 1) / TM;               // 1366 (last block: 16 tokens)
    prep_w2<<<384, 256, 0, stream>>>(Wq, Wk, Wv);
    size_t lds = (size_t)TM * QSTR * sizeof(bf16_t);   // 148224 B
    fused_mha<<<grid, 512, lds, stream>>>(x, out);
}

// Round 21
// 197.708 us; speedup vs baseline: 1.0132x; 1.0132x over previous
//
#include <hip/hip_runtime.h>
#include <hip/hip_bf16.h>

typedef __bf16 bf16_t;
typedef __bf16 bf16x8 __attribute__((ext_vector_type(8)));
typedef float  f32x4  __attribute__((ext_vector_type(4)));

#define DM    512
#define NQKV  1536
#define NTOK  65536
#define TM    48          // tokens per block (3 x 16 m-frags)
#define QSTR  1544        // qkv LDS row stride (elems): 1536 + 8 pad

// Fragment-major repacked weights ("flatmm shuffle"): for wave w (0..7),
// K-step s (0..15), ni (0..11), lane l (0..63), elem e (0..7):
//   ELEM offset = (((w*16+s)*12+ni)*64 + l)*8 + e
//   n = w*192+ni*16+(l&15);  k = s*32+(l>>4)*8+e
// Half-step h (s=h>>1, half=h&1): 6 frags at ELEM offset w*98304 + h*3072.
// R21 split: frags 0-2 of each half-step go through the LDS ring, frags
// 3-5 go direct L2->VGPR (per-lane load of gwB + h*3072 + (3+k)*512).
__device__ __align__(16) bf16_t g_wt2[(size_t)NQKV * DM];

#define MEMFENCE asm volatile("" ::: "memory")

typedef const void __attribute__((address_space(1)))* gas_t;
typedef void       __attribute__((address_space(3)))* sas_t;
__device__ __forceinline__ void gl_lds16(const void* g, void* s) {
    // async global->LDS, 16B/lane; LDS dest = wave-uniform base + lane*16
    __builtin_amdgcn_global_load_lds((gas_t)g, (sas_t)s, 16, 0, 0);
}

// ---------------------------------------------------------------------------
// Kernel 1: scatter W_q|W_k|W_v (fp32 [k][n]) -> g_wt2 fragment-major bf16
// ---------------------------------------------------------------------------
__global__ void prep_w2(const float* __restrict__ Wq,
                        const float* __restrict__ Wk,
                        const float* __restrict__ Wv) {
    int flat = blockIdx.x * 256 + threadIdx.x;   // 0..98303 (one bf16x8 each)
    int l  = flat & 63;
    int kg = l >> 4, lr = l & 15;
    int t2 = flat >> 6;
    int ni = t2 % 12;
    int t3 = t2 / 12;
    int s  = t3 & 15, w = t3 >> 4;
    int n  = w * 192 + ni * 16 + lr;             // 0..1535
    int k0 = s * 32 + kg * 8;
    int mat = n >> 9, nn = n & 511;
    const float* W = (mat == 0) ? Wq : ((mat == 1) ? Wk : Wv);
    bf16x8 v;
#pragma unroll
    for (int e = 0; e < 8; ++e) v[e] = (bf16_t)W[(k0 + e) * DM + nn];
    *(bf16x8*)(g_wt2 + (size_t)flat * 8) = v;
}

// ---------------------------------------------------------------------------
// Kernel 2: fused QKV projection + cross-head attention (R19 base +
// SPLIT-PORT B STREAM). The K-loop was LDS-issue-bound (~4.8x oversubscribed
// vs the matrix pipe -> 21% in-loop MfmaUtil ceiling, matching the measured
// 16%). B frags 0-2 per half-step keep the proven LDS ring (counted vmcnt);
// frags 3-5 load direct L2->VGPR, double-buffered 1 half-step ahead (~450cy
// cover > L2 latency; 24 VGPR so no compiler serialization). LDS traffic
// drops ~40%; the two operand streams use independent ports.
// vmcnt: per-step issue order [regB(h+1) x3, ring(h+2) x3] => WAITVM(3)
// retires exactly ring(h)+regB(h), leaving ring(h+1) in flight.
// LDS: A [0,48K) | ring [48K,96K) (8 waves x 2 slots x 3072 B) | qkv overlay.
// ---------------------------------------------------------------------------
__global__ __launch_bounds__(512, 1) void fused_mha(
    const float* __restrict__ x, float* __restrict__ out) {
    extern __shared__ char sm[];        // 148224 B

    const int tid = threadIdx.x;
    const int l   = tid & 63, w = tid >> 6;
    const int lr  = l & 15,  kg = l >> 4;
    const size_t tok0 = (size_t)blockIdx.x * TM;
    const int ntb = (int)(((size_t)NTOK - tok0) < TM ? (NTOK - tok0) : TM);

    // ---- stage x tile: fp32 global -> bf16 LDS, 16B-chunk XOR swizzle ------
    {
        const int rbase = tid >> 5;               // 0..15
        const int cj    = tid & 31;
#pragma unroll
        for (int p = 0; p < 3; ++p) {
            int r = p * 16 + rbase;               // 0..47
            int r7 = r & 7;
            if (r < ntb) {
                const float* xp = x + (tok0 + r) * DM;
#pragma unroll
                for (int jj = 0; jj < 2; ++jj) {
                    int c = cj + jj * 32;         // chunk 0..63 (8 bf16 each)
                    float4 f0 = *(const float4*)(xp + c * 8);
                    float4 f1 = *(const float4*)(xp + c * 8 + 4);
                    bf16x8 v;
                    v[0] = (bf16_t)f0.x; v[1] = (bf16_t)f0.y;
                    v[2] = (bf16_t)f0.z; v[3] = (bf16_t)f0.w;
                    v[4] = (bf16_t)f1.x; v[5] = (bf16_t)f1.y;
                    v[6] = (bf16_t)f1.z; v[7] = (bf16_t)f1.w;
                    *(bf16x8*)(sm + r * 1024 + ((c ^ r7) << 4)) = v;
                }
            } else {                               // remainder block: zero rows
                bf16x8 z;
#pragma unroll
                for (int e = 0; e < 8; ++e) z[e] = (bf16_t)0.f;
#pragma unroll
                for (int jj = 0; jj < 2; ++jj) {
                    int c = cj + jj * 32;
                    *(bf16x8*)(sm + r * 1024 + ((c ^ r7) << 4)) = z;
                }
            }
        }
    }

    // ---- B ring: 2 slots x 3072 B per wave at sm+49152 (frags 0-2) --------
    const bf16_t* gwB = g_wt2 + (size_t)w * 98304 + l * 8;   // elem offsets
    char* ringW = sm + 49152 + w * 6144;                      // wave-uniform

#define ISSUE3(h_)                                                            \
    do {                                                                      \
        _Pragma("unroll")                                                     \
        for (int ii = 0; ii < 3; ++ii)                                        \
            gl_lds16(gwB + (size_t)(h_) * 3072 + ii * 512,                    \
                     ringW + ((h_) & 1) * 3072 + ii * 1024);                  \
    } while (0)
#define LOADRB(B_, h_)                                                        \
    do {                                                                      \
        _Pragma("unroll")                                                     \
        for (int k = 0; k < 3; ++k)                                           \
            B_[k] = *(const bf16x8*)(gwB + (size_t)(h_) * 3072 +              \
                                     (3 + k) * 512);                          \
    } while (0)
#define WAITVM(n_) asm volatile("s_waitcnt vmcnt(" #n_ ")" ::: "memory")

    bf16x8 rB0[3], rB1[3];

    // prologue (order fixes the vmcnt count): ring(0), regB(0), ring(1)
    ISSUE3(0);
    __builtin_amdgcn_sched_barrier(0);
    LOADRB(rB0, 0);
    __builtin_amdgcn_sched_barrier(0);
    ISSUE3(1);
    __builtin_amdgcn_sched_barrier(0);
    asm volatile("s_waitcnt lgkmcnt(0)" ::: "memory");  // x ds_writes drained
    __builtin_amdgcn_s_barrier();
    MEMFENCE;

    // ---- barrier-free K-loop: 32 half-steps, fully unrolled ----------------
    f32x4 acc[3][12];
#pragma unroll
    for (int a = 0; a < 3; ++a)
#pragma unroll
        for (int b = 0; b < 12; ++b) acc[a][b] = (f32x4){0.f, 0.f, 0.f, 0.f};

    const int sx = (lr & 7) << 4;               // A-read swizzle term
    bf16x8 af[3];

#define HSTEP(h_, vm_, BCUR, BNXT)                                            \
    do {                                                                      \
        WAITVM(vm_);       /* retires ring(h_) + regB(h_) (6 oldest) */       \
        bf16x8 bf_[3];                                                        \
        _Pragma("unroll")                                                     \
        for (int ni = 0; ni < 3; ++ni)                                        \
            bf_[ni] = *(const bf16x8*)(ringW + ((h_) & 1) * 3072 +            \
                                       ni * 1024 + l * 16);                   \
        if (((h_) & 1) == 0) {                                                \
            _Pragma("unroll")                                                 \
            for (int mi = 0; mi < 3; ++mi)                                    \
                af[mi] = *(const bf16x8*)(sm + (mi * 16 + lr) * 1024 +        \
                                          ((((h_) >> 1) * 64 + kg * 16) ^ sx)); \
        }                                                                     \
        asm volatile("s_waitcnt lgkmcnt(0)" ::: "memory");                    \
        __builtin_amdgcn_sched_barrier(0);      /* rule #18 */                \
        if ((h_) + 1 < 32) LOADRB(BNXT, (h_) + 1);                            \
        __builtin_amdgcn_sched_barrier(0);      /* pin issue order */         \
        if ((h_) + 2 < 32) ISSUE3((h_) + 2);                                  \
        __builtin_amdgcn_sched_barrier(0);                                    \
        __builtin_amdgcn_s_setprio(1);                                        \
        _Pragma("unroll")                                                     \
        for (int mi = 0; mi < 3; ++mi) {                                      \
            _Pragma("unroll")                                                 \
            for (int ni = 0; ni < 3; ++ni)                                    \
                acc[mi][((h_) & 1) * 6 + ni] =                                \
                    __builtin_amdgcn_mfma_f32_16x16x32_bf16(                  \
                        af[mi], bf_[ni], acc[mi][((h_) & 1) * 6 + ni],        \
                        0, 0, 0);                                             \
            _Pragma("unroll")                                                 \
            for (int k = 0; k < 3; ++k)                                       \
                acc[mi][((h_) & 1) * 6 + 3 + k] =                             \
                    __builtin_amdgcn_mfma_f32_16x16x32_bf16(                  \
                        af[mi], BCUR[k], acc[mi][((h_) & 1) * 6 + 3 + k],     \
                        0, 0, 0);                                             \
        }                                                                     \
        __builtin_amdgcn_s_setprio(0);                                        \
    } while (0)

    HSTEP( 0, 3, rB0, rB1); HSTEP( 1, 3, rB1, rB0);
    HSTEP( 2, 3, rB0, rB1); HSTEP( 3, 3, rB1, rB0);
    HSTEP( 4, 3, rB0, rB1); HSTEP( 5, 3, rB1, rB0);
    HSTEP( 6, 3, rB0, rB1); HSTEP( 7, 3, rB1, rB0);
    HSTEP( 8, 3, rB0, rB1); HSTEP( 9, 3, rB1, rB0);
    HSTEP(10, 3, rB0, rB1); HSTEP(11, 3, rB1, rB0);
    HSTEP(12, 3, rB0, rB1); HSTEP(13, 3, rB1, rB0);
    HSTEP(14, 3, rB0, rB1); HSTEP(15, 3, rB1, rB0);
    HSTEP(16, 3, rB0, rB1); HSTEP(17, 3, rB1, rB0);
    HSTEP(18, 3, rB0, rB1); HSTEP(19, 3, rB1, rB0);
    HSTEP(20, 3, rB0, rB1); HSTEP(21, 3, rB1, rB0);
    HSTEP(22, 3, rB0, rB1); HSTEP(23, 3, rB1, rB0);
    HSTEP(24, 3, rB0, rB1); HSTEP(25, 3, rB1, rB0);
    HSTEP(26, 3, rB0, rB1); HSTEP(27, 3, rB1, rB0);
    HSTEP(28, 3, rB0, rB1); HSTEP(29, 3, rB1, rB0);
    HSTEP(30, 3, rB0, rB1); HSTEP(31, 0, rB1, rB0);
#undef HSTEP
#undef ISSUE3
#undef LOADRB
#undef WAITVM

    // ---- A + ring dead; full drain + sync before qkv overlays --------------
    asm volatile("s_waitcnt vmcnt(0) lgkmcnt(0)" ::: "memory");
    __builtin_amdgcn_s_barrier();
    MEMFENCE;

    // ---- epilogue: acc -> qkv LDS [48][QSTR] (row = token, col = n) --------
    bf16_t* qkv = (bf16_t*)sm;
#pragma unroll
    for (int mi = 0; mi < 3; ++mi)
#pragma unroll
        for (int ni = 0; ni < 12; ++ni) {
            int col = w * 192 + ni * 16 + lr;
#pragma unroll
            for (int i = 0; i < 4; ++i) {
                int token = mi * 16 + kg * 4 + i;
                qkv[token * QSTR + col] = (bf16_t)acc[mi][ni][i];
            }
        }
    asm volatile("s_waitcnt lgkmcnt(0)" ::: "memory");
    __builtin_amdgcn_s_barrier();
    MEMFENCE;

    // ---- attention: 16 threads/token, two passes (0..31, 32..47) ----------
#pragma unroll
    for (int p = 0; p < 2; ++p) {
        const int tok = p * 32 + (tid >> 4);
        if (tok < ntb) {
            const int tj = tid & 15, h = tj & 7, d0 = (tj >> 3) << 5;
            const bf16_t* base = qkv + tok * QSTR;

            float qv[32];
            {
                const bf16_t* qp = base + h * 64 + d0;
#pragma unroll
                for (int j = 0; j < 4; ++j) {
                    bf16x8 q8 = *(const bf16x8*)(qp + 8 * j);
#pragma unroll
                    for (int e = 0; e < 8; ++e) qv[8 * j + e] = (float)q8[e];
                }
            }

            float s[8];
#pragma unroll
            for (int t = 0; t < 8; ++t) {
                const bf16_t* kp = base + 512 + t * 64 + d0;
                float a = 0.f;
#pragma unroll
                for (int j = 0; j < 4; ++j) {
                    bf16x8 k8 = *(const bf16x8*)(kp + 8 * j);
#pragma unroll
                    for (int e = 0; e < 8; ++e) a += qv[8 * j + e] * (float)k8[e];
                }
                s[t] = a;
            }
            // combine two d-halves (partner lane tid^8: same tok, same h)
#pragma unroll
            for (int t = 0; t < 8; ++t) s[t] += __shfl_xor(s[t], 8, 64);

            float m = s[0];
#pragma unroll
            for (int t = 1; t < 8; ++t) m = fmaxf(m, s[t]);
            float pr[8], psum = 0.f;
#pragma unroll
            for (int t = 0; t < 8; ++t) {
                pr[t] = exp2f((s[t] - m) * 1.44269504088896f);
                psum += pr[t];
            }
            float inv = 1.0f / psum;

            float o[32];
#pragma unroll
            for (int e = 0; e < 32; ++e) o[e] = 0.f;
#pragma unroll
            for (int t = 0; t < 8; ++t) {
                float pt = pr[t] * inv;
                const bf16_t* vp = base + 1024 + t * 64 + d0;
#pragma unroll
                for (int j = 0; j < 4; ++j) {
                    bf16x8 v8 = *(const bf16x8*)(vp + 8 * j);
#pragma unroll
                    for (int e = 0; e < 8; ++e) o[8 * j + e] += pt * (float)v8[e];
                }
            }

            float* op = out + (tok0 + tok) * DM + h * 64 + d0;
#pragma unroll
            for (int j = 0; j < 8; ++j) {
                float4 o4 = {o[4 * j], o[4 * j + 1], o[4 * j + 2], o[4 * j + 3]};
                *(float4*)(op + 4 * j) = o4;
            }
        }
    }
}

// ---------------------------------------------------------------------------
extern "C" void kernel_launch(void* const* d_in, const int* in_sizes, int n_in,
                              void* d_out, int out_size, void* d_ws, size_t ws_size,
                              hipStream_t stream) {
    (void)d_ws; (void)ws_size; (void)n_in; (void)out_size;
    const float* x  = (const float*)d_in[0];
    const float* Wq = (const float*)d_in[1];
    const float* Wk = (const float*)d_in[2];
    const float* Wv = (const float*)d_in[3];
    float* out = (float*)d_out;

    int ntok = in_sizes[0] / DM;                   // 65536
    int grid = (ntok + TM - 1) / TM;               // 1366 (last block: 16 tokens)
    prep_w2<<<384, 256, 0, stream>>>(Wq, Wk, Wv);
    size_t lds = (size_t)TM * QSTR * sizeof(bf16_t);   // 148224 B
    fused_mha<<<grid, 512, lds, stream>>>(x, out);
}